// Round 4
// baseline (1863.999 us; speedup 1.0000x reference)
//
#include <hip/hip_runtime.h>
#include <hip/hip_bf16.h>

#define BB 4
#define LL 256
#define PP 1024
#define DD 512
#define HH 8
#define HD 64
#define NRBF 50

// ---------------------------------------------------------------------------
// dtype helpers (inputs are fp32 per reference; bf16 fallback kept for safety)
// ---------------------------------------------------------------------------
__device__ __forceinline__ float ldf(const void* p, size_t i, bool f32) {
  if (f32) return ((const float*)p)[i];
  return __bfloat162float(((const __hip_bfloat16*)p)[i]);
}

__global__ __launch_bounds__(256) void detect_dtype(const float* q, int* flag) {
  __shared__ int cnt;
  if (threadIdx.x == 0) cnt = 0;
  __syncthreads();
  int c = 0;
  for (int i = threadIdx.x; i < 1024; i += 256) {
    unsigned u = __float_as_uint(q[i]);
    unsigned e = (u >> 23) & 0xffu;
    if (e >= 104u && e <= 140u) c++;
  }
  atomicAdd(&cnt, c);
  __syncthreads();
  if (threadIdx.x == 0) *flag = (cnt > 512) ? 1 : 0;
}

// ---------------------------------------------------------------------------
// rbf bias: biasW[b,l,h,p] = rbf[b,l,p,:] @ Wr[:,h] + br[h].  Memory-bound.
// ---------------------------------------------------------------------------
__global__ __launch_bounds__(256) void rbf_bias_kernel(
    const void* __restrict__ rbf, const void* __restrict__ Wr,
    const void* __restrict__ br, float* __restrict__ biasW,
    const int* __restrict__ flag) {
  const bool f32 = (*flag != 0);
  __shared__ float wrS[NRBF * 8];
  __shared__ float brS[8];
  const int tid = threadIdx.x;
  for (int i = tid; i < NRBF * 8; i += 256) wrS[i] = ldf(Wr, i, f32);
  if (tid < 8) brS[tid] = ldf(br, tid, f32);
  __syncthreads();
  const size_t row = (size_t)blockIdx.x * 256 + tid;  // (b*L+l)*P + p
  float acc[8];
#pragma unroll
  for (int h = 0; h < 8; ++h) acc[h] = brS[h];
  if (f32) {
    const float2* rp = (const float2*)((const float*)rbf + row * NRBF);
#pragma unroll
    for (int j = 0; j < 25; ++j) {
      float2 r2 = rp[j];
      float4 wa = *(const float4*)&wrS[(2 * j) * 8];
      float4 wb = *(const float4*)&wrS[(2 * j) * 8 + 4];
      float4 wc = *(const float4*)&wrS[(2 * j + 1) * 8];
      float4 wd = *(const float4*)&wrS[(2 * j + 1) * 8 + 4];
      acc[0] = fmaf(r2.x, wa.x, acc[0]); acc[1] = fmaf(r2.x, wa.y, acc[1]);
      acc[2] = fmaf(r2.x, wa.z, acc[2]); acc[3] = fmaf(r2.x, wa.w, acc[3]);
      acc[4] = fmaf(r2.x, wb.x, acc[4]); acc[5] = fmaf(r2.x, wb.y, acc[5]);
      acc[6] = fmaf(r2.x, wb.z, acc[6]); acc[7] = fmaf(r2.x, wb.w, acc[7]);
      acc[0] = fmaf(r2.y, wc.x, acc[0]); acc[1] = fmaf(r2.y, wc.y, acc[1]);
      acc[2] = fmaf(r2.y, wc.z, acc[2]); acc[3] = fmaf(r2.y, wc.w, acc[3]);
      acc[4] = fmaf(r2.y, wd.x, acc[4]); acc[5] = fmaf(r2.y, wd.y, acc[5]);
      acc[6] = fmaf(r2.y, wd.z, acc[6]); acc[7] = fmaf(r2.y, wd.w, acc[7]);
    }
  } else {
    const __hip_bfloat16* rb = (const __hip_bfloat16*)rbf + row * NRBF;
#pragma unroll
    for (int j = 0; j < NRBF; ++j) {
      float r = __bfloat162float(rb[j]);
#pragma unroll
      for (int h = 0; h < 8; ++h) acc[h] = fmaf(r, wrS[j * 8 + h], acc[h]);
    }
  }
  const size_t bl = row >> 10;
  const int p = (int)(row & 1023);
#pragma unroll
  for (int h = 0; h < 8; ++h) biasW[(bl * 8 + h) * 1024 + p] = acc[h];
}

// ---------------------------------------------------------------------------
// Input projection: Y = X@W + b.  kt=0: Y[m][512] fp32.
// kt=1: transposed head-major output Kt[b][h][d][p] (m = b*1024+p, n = h*64+d)
// ---------------------------------------------------------------------------
__global__ __launch_bounds__(256) void proj_in(
    const void* __restrict__ X, const void* __restrict__ W,
    const void* __restrict__ bias, float* __restrict__ Y,
    const int* __restrict__ flag, const int kt) {
  __shared__ float As[16][64];  // [k][m]
  __shared__ float Bs[16][64];  // [k][n]
  const bool f32 = (*flag != 0);
  const int bm = blockIdx.x * 64, bn = blockIdx.y * 64;
  const int tid = threadIdx.x;
  const int tx = tid & 15, ty = tid >> 4;
  float acc[4][4] = {};
  for (int k0 = 0; k0 < 512; k0 += 16) {
    if (f32) {
      const float* Xf = (const float*)X;
      const float* Wf = (const float*)W;
      {
        int r = tid >> 2, kf = (tid & 3) * 4;
        float4 x4 = *(const float4*)(Xf + (size_t)(bm + r) * 512 + k0 + kf);
        As[kf + 0][r] = x4.x; As[kf + 1][r] = x4.y;
        As[kf + 2][r] = x4.z; As[kf + 3][r] = x4.w;
      }
      {
        int kk = tid >> 4, cf = (tid & 15) * 4;
        *(float4*)&Bs[kk][cf] =
            *(const float4*)(Wf + (size_t)(k0 + kk) * 512 + bn + cf);
      }
    } else {
      const __hip_bfloat16* Xb = (const __hip_bfloat16*)X;
      const __hip_bfloat16* Wb = (const __hip_bfloat16*)W;
      for (int f = tid; f < 64 * 16; f += 256) {
        int r = f >> 4, kk = f & 15;
        As[kk][r] = __bfloat162float(Xb[(size_t)(bm + r) * 512 + k0 + kk]);
      }
      for (int f = tid; f < 16 * 64; f += 256) {
        int kk = f >> 6, c = f & 63;
        Bs[kk][c] = __bfloat162float(Wb[(size_t)(k0 + kk) * 512 + bn + c]);
      }
    }
    __syncthreads();
#pragma unroll
    for (int k = 0; k < 16; ++k) {
      float4 a4 = *(const float4*)&As[k][ty * 4];
      float4 b4 = *(const float4*)&Bs[k][tx * 4];
      acc[0][0] = fmaf(a4.x, b4.x, acc[0][0]); acc[0][1] = fmaf(a4.x, b4.y, acc[0][1]);
      acc[0][2] = fmaf(a4.x, b4.z, acc[0][2]); acc[0][3] = fmaf(a4.x, b4.w, acc[0][3]);
      acc[1][0] = fmaf(a4.y, b4.x, acc[1][0]); acc[1][1] = fmaf(a4.y, b4.y, acc[1][1]);
      acc[1][2] = fmaf(a4.y, b4.z, acc[1][2]); acc[1][3] = fmaf(a4.y, b4.w, acc[1][3]);
      acc[2][0] = fmaf(a4.z, b4.x, acc[2][0]); acc[2][1] = fmaf(a4.z, b4.y, acc[2][1]);
      acc[2][2] = fmaf(a4.z, b4.z, acc[2][2]); acc[2][3] = fmaf(a4.z, b4.w, acc[2][3]);
      acc[3][0] = fmaf(a4.w, b4.x, acc[3][0]); acc[3][1] = fmaf(a4.w, b4.y, acc[3][1]);
      acc[3][2] = fmaf(a4.w, b4.z, acc[3][2]); acc[3][3] = fmaf(a4.w, b4.w, acc[3][3]);
    }
    __syncthreads();
  }
  if (kt) {
    // Kt[b][h][d][p]: h = bn>>6, d = tx*4+j, p = (bm&1023)+ty*4+i, b = bm>>10
    const int h = bn >> 6;
    const int bq = bm >> 10;
    const int p0 = (bm & 1023) + ty * 4;
#pragma unroll
    for (int j = 0; j < 4; ++j) {
      const float bb = ldf(bias, bn + tx * 4 + j, f32);
      float4 pv;
      pv.x = acc[0][j] + bb; pv.y = acc[1][j] + bb;
      pv.z = acc[2][j] + bb; pv.w = acc[3][j] + bb;
      *(float4*)(Y + (((size_t)bq * 8 + h) * 64 + tx * 4 + j) * 1024 + p0) = pv;
    }
  } else {
#pragma unroll
    for (int i = 0; i < 4; ++i) {
      int r = bm + ty * 4 + i;
      float4 o;
      o.x = acc[i][0] + ldf(bias, bn + tx * 4 + 0, f32);
      o.y = acc[i][1] + ldf(bias, bn + tx * 4 + 1, f32);
      o.z = acc[i][2] + ldf(bias, bn + tx * 4 + 2, f32);
      o.w = acc[i][3] + ldf(bias, bn + tx * 4 + 3, f32);
      *(float4*)(Y + (size_t)r * 512 + bn + tx * 4) = o;
    }
  }
}

// ---------------------------------------------------------------------------
// Output projection + residual: Xout = AO@Wo + bo + query   (fp32 ws)
// ---------------------------------------------------------------------------
__global__ __launch_bounds__(256) void proj_out(
    const float* __restrict__ X, const void* __restrict__ W,
    const void* __restrict__ bias, const void* __restrict__ resid,
    float* __restrict__ Y, const int* __restrict__ flag) {
  __shared__ float As[16][64];
  __shared__ float Bs[16][64];
  const bool f32 = (*flag != 0);
  const int bm = blockIdx.x * 64, bn = blockIdx.y * 64;
  const int tid = threadIdx.x;
  const int tx = tid & 15, ty = tid >> 4;
  float acc[4][4] = {};
  for (int k0 = 0; k0 < 512; k0 += 16) {
    {
      int r = tid >> 2, kf = (tid & 3) * 4;
      float4 x4 = *(const float4*)(X + (size_t)(bm + r) * 512 + k0 + kf);
      As[kf + 0][r] = x4.x; As[kf + 1][r] = x4.y;
      As[kf + 2][r] = x4.z; As[kf + 3][r] = x4.w;
    }
    if (f32) {
      int kk = tid >> 4, cf = (tid & 15) * 4;
      *(float4*)&Bs[kk][cf] =
          *(const float4*)((const float*)W + (size_t)(k0 + kk) * 512 + bn + cf);
    } else {
      const __hip_bfloat16* Wb = (const __hip_bfloat16*)W;
      for (int f = tid; f < 16 * 64; f += 256) {
        int kk = f >> 6, c = f & 63;
        Bs[kk][c] = __bfloat162float(Wb[(size_t)(k0 + kk) * 512 + bn + c]);
      }
    }
    __syncthreads();
#pragma unroll
    for (int k = 0; k < 16; ++k) {
      float4 a4 = *(const float4*)&As[k][ty * 4];
      float4 b4 = *(const float4*)&Bs[k][tx * 4];
      acc[0][0] = fmaf(a4.x, b4.x, acc[0][0]); acc[0][1] = fmaf(a4.x, b4.y, acc[0][1]);
      acc[0][2] = fmaf(a4.x, b4.z, acc[0][2]); acc[0][3] = fmaf(a4.x, b4.w, acc[0][3]);
      acc[1][0] = fmaf(a4.y, b4.x, acc[1][0]); acc[1][1] = fmaf(a4.y, b4.y, acc[1][1]);
      acc[1][2] = fmaf(a4.y, b4.z, acc[1][2]); acc[1][3] = fmaf(a4.y, b4.w, acc[1][3]);
      acc[2][0] = fmaf(a4.z, b4.x, acc[2][0]); acc[2][1] = fmaf(a4.z, b4.y, acc[2][1]);
      acc[2][2] = fmaf(a4.z, b4.z, acc[2][2]); acc[2][3] = fmaf(a4.z, b4.w, acc[2][3]);
      acc[3][0] = fmaf(a4.w, b4.x, acc[3][0]); acc[3][1] = fmaf(a4.w, b4.y, acc[3][1]);
      acc[3][2] = fmaf(a4.w, b4.z, acc[3][2]); acc[3][3] = fmaf(a4.w, b4.w, acc[3][3]);
    }
    __syncthreads();
  }
#pragma unroll
  for (int i = 0; i < 4; ++i) {
    int r = bm + ty * 4 + i;
    float4 o;
#pragma unroll
    for (int j = 0; j < 4; ++j) {
      int c = bn + tx * 4 + j;
      float v = acc[i][j] + ldf(bias, c, f32) +
                ldf(resid, (size_t)r * 512 + c, f32);
      ((float*)&o)[j] = v;
    }
    *(float4*)(Y + (size_t)r * 512 + bn + tx * 4) = o;
  }
}

// ---------------------------------------------------------------------------
// Attention v4: coalesced Kt reads, precomputed bias, LDS 38 KB, 4 barriers.
// One block per (b,l); thread owns p-quad 4t..4t+3 in the score phase.
// ---------------------------------------------------------------------------
__global__ __launch_bounds__(256, 4) void attn_v4(
    const float* __restrict__ Q,     // [B*L, 512]
    const float* __restrict__ Kt,    // [B][8][64][1024]
    const float* __restrict__ V,     // [B*P, 512]
    const float* __restrict__ biasW, // [B*L][8][1024]
    const int* __restrict__ mask,    // [B,P]
    float* __restrict__ AO,          // [B*L, 512]
    void* __restrict__ d_out, const int* __restrict__ flag) {
  const int xcd = blockIdx.x & 7;
  const int idx = blockIdx.x >> 3;
  const int b = xcd >> 1;
  const int l = ((xcd & 1) << 7) | idx;
  const int bl = b * LL + l;
  const int t = threadIdx.x;
  const bool f32 = (*flag != 0);

  __shared__ float qS[512];
  __shared__ float scoresS[HH * PP];   // 32 KB
  __shared__ float partsS[2 * 128 * 4]; // 4 KB

  for (int i = t; i < 512; i += 256) qS[i] = Q[(size_t)bl * 512 + i];
  __syncthreads();

  // ---- score phase: thread owns p in {4t..4t+3}, loops all 8 heads ----
  {
    const int4 mk4 = *(const int4*)(mask + b * PP + 4 * t);
    for (int h = 0; h < 8; ++h) {
      float4 qf[16];
#pragma unroll
      for (int dq = 0; dq < 16; ++dq)
        qf[dq] = *(const float4*)&qS[h * 64 + dq * 4];
      const float4* ktp =
          (const float4*)(Kt + (((size_t)b * 8 + h) * 64) * 1024) + t;
      float4 acc = {0.f, 0.f, 0.f, 0.f};
#pragma unroll
      for (int dq = 0; dq < 16; ++dq) {
#pragma unroll
        for (int e = 0; e < 4; ++e) {
          const float qv = ((const float*)&qf[dq])[e];
          float4 k4 = ktp[(size_t)(dq * 4 + e) * 256];
          acc.x = fmaf(qv, k4.x, acc.x);
          acc.y = fmaf(qv, k4.y, acc.y);
          acc.z = fmaf(qv, k4.z, acc.z);
          acc.w = fmaf(qv, k4.w, acc.w);
        }
      }
      float4 b4 = *(const float4*)&biasW[((size_t)bl * 8 + h) * 1024 + 4 * t];
      float4 s;
      s.x = (mk4.x == 0) ? -1e9f : fmaf(acc.x, 0.125f, b4.x);
      s.y = (mk4.y == 0) ? -1e9f : fmaf(acc.y, 0.125f, b4.y);
      s.z = (mk4.z == 0) ? -1e9f : fmaf(acc.z, 0.125f, b4.z);
      s.w = (mk4.w == 0) ? -1e9f : fmaf(acc.w, 0.125f, b4.w);
      *(float4*)&scoresS[h * 1024 + 4 * t] = s;
    }
  }
  __syncthreads();

  // ---- softmax per head; wave w handles heads 2w,2w+1 ----
  const int wave = t >> 6, lane = t & 63;
  for (int hh = wave * 2; hh < wave * 2 + 2; ++hh) {
    float* sc = &scoresS[hh * 1024];
    float m = -3.0e38f;
    for (int i = lane; i < PP; i += 64) m = fmaxf(m, sc[i]);
#pragma unroll
    for (int off = 32; off; off >>= 1) m = fmaxf(m, __shfl_xor(m, off, 64));
    float sum = 0.f;
    for (int i = lane; i < PP; i += 64) {
      float e = __expf(sc[i] - m);
      sc[i] = e;
      sum += e;
    }
#pragma unroll
    for (int off = 32; off; off >>= 1) sum += __shfl_xor(sum, off, 64);
    const float inv = 1.0f / sum;
    for (int i = lane; i < PP; i += 64) sc[i] *= inv;
  }
  __syncthreads();

  // ---- attn_mean: thread owns 4 consecutive p ----
  {
    float4 s = {0.f, 0.f, 0.f, 0.f};
#pragma unroll
    for (int hh = 0; hh < HH; ++hh) {
      float4 v = *(const float4*)&scoresS[hh * 1024 + t * 4];
      s.x += v.x; s.y += v.y; s.z += v.z; s.w += v.w;
    }
    s.x *= 0.125f; s.y *= 0.125f; s.z *= 0.125f; s.w *= 0.125f;
    const size_t base = (size_t)BB * LL * DD + (size_t)bl * PP + t * 4;
    if (f32) {
      *(float4*)((float*)d_out + base) = s;
    } else {
      __hip_bfloat16* o1 = (__hip_bfloat16*)d_out;
      o1[base + 0] = __float2bfloat16(s.x);
      o1[base + 1] = __float2bfloat16(s.y);
      o1[base + 2] = __float2bfloat16(s.z);
      o1[base + 3] = __float2bfloat16(s.w);
    }
  }

  // ---- PV: thread owns c-quad (cq = t&127) and p-half (ph = t>>7) ----
  {
    const int cq = t & 127;
    const int ph = t >> 7;
    const int h = cq >> 4;
    const float* sc = &scoresS[h * 1024];
    const float4* Vb =
        (const float4*)(V + (size_t)b * PP * 512) + cq;  // stride 128 f4 per p
    float4 acc = {0.f, 0.f, 0.f, 0.f};
    const int p0 = ph * 512;
    for (int p4 = p0; p4 < p0 + 512; p4 += 4) {
      float4 pr = *(const float4*)&sc[p4];
      float4 v0 = Vb[(size_t)(p4 + 0) * 128];
      float4 v1 = Vb[(size_t)(p4 + 1) * 128];
      float4 v2 = Vb[(size_t)(p4 + 2) * 128];
      float4 v3 = Vb[(size_t)(p4 + 3) * 128];
      acc.x = fmaf(pr.x, v0.x, acc.x); acc.y = fmaf(pr.x, v0.y, acc.y);
      acc.z = fmaf(pr.x, v0.z, acc.z); acc.w = fmaf(pr.x, v0.w, acc.w);
      acc.x = fmaf(pr.y, v1.x, acc.x); acc.y = fmaf(pr.y, v1.y, acc.y);
      acc.z = fmaf(pr.y, v1.z, acc.z); acc.w = fmaf(pr.y, v1.w, acc.w);
      acc.x = fmaf(pr.z, v2.x, acc.x); acc.y = fmaf(pr.z, v2.y, acc.y);
      acc.z = fmaf(pr.z, v2.z, acc.z); acc.w = fmaf(pr.z, v2.w, acc.w);
      acc.x = fmaf(pr.w, v3.x, acc.x); acc.y = fmaf(pr.w, v3.y, acc.y);
      acc.z = fmaf(pr.w, v3.z, acc.z); acc.w = fmaf(pr.w, v3.w, acc.w);
    }
    *(float4*)&partsS[(ph * 128 + cq) * 4] = acc;
  }
  __syncthreads();
  if (t < 128) {
    float4 a = *(const float4*)&partsS[t * 4];
    float4 bb = *(const float4*)&partsS[(128 + t) * 4];
    a.x += bb.x; a.y += bb.y; a.z += bb.z; a.w += bb.w;
    *(float4*)(AO + (size_t)bl * 512 + t * 4) = a;
  }
}

// ---------------------------------------------------------------------------
// LayerNorm rows of Xw -> out0
// ---------------------------------------------------------------------------
__global__ __launch_bounds__(256) void ln_kernel(
    const float* __restrict__ Xw, const void* __restrict__ gamma,
    const void* __restrict__ beta, void* __restrict__ d_out,
    const int* __restrict__ flag) {
  const int bl = blockIdx.x;
  const int tid = threadIdx.x;
  const bool f32 = (*flag != 0);
  __shared__ float red[16];
  float v0 = Xw[(size_t)bl * 512 + tid];
  float v1 = Xw[(size_t)bl * 512 + tid + 256];
  float s = v0 + v1, s2 = v0 * v0 + v1 * v1;
#pragma unroll
  for (int off = 32; off; off >>= 1) {
    s += __shfl_xor(s, off, 64);
    s2 += __shfl_xor(s2, off, 64);
  }
  const int wave = tid >> 6, lane = tid & 63;
  if (lane == 0) { red[wave] = s; red[8 + wave] = s2; }
  __syncthreads();
  if (tid == 0) {
    float ts = 0.f, ts2 = 0.f;
    for (int w = 0; w < 4; ++w) { ts += red[w]; ts2 += red[8 + w]; }
    red[0] = ts; red[1] = ts2;
  }
  __syncthreads();
  const float mu = red[0] * (1.0f / 512.0f);
  const float var = red[1] * (1.0f / 512.0f) - mu * mu;
  const float rstd = rsqrtf(var + 1e-5f);
  float o0 = (v0 - mu) * rstd * ldf(gamma, tid, f32) + ldf(beta, tid, f32);
  float o1 = (v1 - mu) * rstd * ldf(gamma, tid + 256, f32) +
             ldf(beta, tid + 256, f32);
  if (f32) {
    float* o = (float*)d_out;
    o[(size_t)bl * 512 + tid] = o0;
    o[(size_t)bl * 512 + tid + 256] = o1;
  } else {
    __hip_bfloat16* o = (__hip_bfloat16*)d_out;
    o[(size_t)bl * 512 + tid] = __float2bfloat16(o0);
    o[(size_t)bl * 512 + tid + 256] = __float2bfloat16(o1);
  }
}

// ---------------------------------------------------------------------------
extern "C" void kernel_launch(void* const* d_in, const int* in_sizes, int n_in,
                              void* d_out, int out_size, void* d_ws,
                              size_t ws_size, hipStream_t stream) {
  const void* query = d_in[0];
  const void* key = d_in[1];
  const void* value = d_in[2];
  const void* rbf = d_in[3];
  const int* key_mask = (const int*)d_in[4];
  const void* Wq = d_in[5];
  const void* bq = d_in[6];
  const void* Wk = d_in[7];
  const void* bk = d_in[8];
  const void* Wv = d_in[9];
  const void* bv = d_in[10];
  const void* Wr = d_in[11];
  const void* br = d_in[12];
  const void* Wo = d_in[13];
  const void* bo = d_in[14];
  const void* gamma = d_in[15];
  const void* beta = d_in[16];

  // ws: [flag 16B] Q | Kt | V | AO | X | biasW
  int* flag = (int*)d_ws;
  float* base = (float*)d_ws + 4;
  float* Qw = base;
  float* Ktw = Qw + (size_t)BB * LL * DD;   // +524288
  float* Vw = Ktw + (size_t)BB * PP * DD;   // +2097152
  float* AO = Vw + (size_t)BB * PP * DD;    // +2097152
  float* Xw = AO + (size_t)BB * LL * DD;    // +524288
  float* biasW = Xw + (size_t)BB * LL * DD; // +524288

  detect_dtype<<<1, 256, 0, stream>>>((const float*)query, flag);
  proj_in<<<dim3(16, 8), 256, 0, stream>>>(query, Wq, bq, Qw, flag, 0);
  proj_in<<<dim3(64, 8), 256, 0, stream>>>(key, Wk, bk, Ktw, flag, 1);
  proj_in<<<dim3(64, 8), 256, 0, stream>>>(value, Wv, bv, Vw, flag, 0);
  rbf_bias_kernel<<<dim3(BB * LL * PP / 256), 256, 0, stream>>>(rbf, Wr, br,
                                                                biasW, flag);
  attn_v4<<<dim3(BB * LL), 256, 0, stream>>>(Qw, Ktw, Vw, biasW, key_mask, AO,
                                             d_out, flag);
  proj_out<<<dim3(16, 8), 256, 0, stream>>>(AO, Wo, bo, query, Xw, flag);
  ln_kernel<<<dim3(BB * LL), 256, 0, stream>>>(Xw, gamma, beta, d_out, flag);
}

// Round 5
// 698.090 us; speedup vs baseline: 2.6701x; 2.6701x over previous
//
#include <hip/hip_runtime.h>
#include <hip/hip_bf16.h>

#define BB 4
#define LL 256
#define PP 1024
#define DD 512
#define HH 8
#define HD 64
#define NRBF 50

// ---------------------------------------------------------------------------
// dtype helpers (inputs are fp32 per reference; bf16 fallback kept for safety)
// ---------------------------------------------------------------------------
__device__ __forceinline__ float ldf(const void* p, size_t i, bool f32) {
  if (f32) return ((const float*)p)[i];
  return __bfloat162float(((const __hip_bfloat16*)p)[i]);
}

__global__ __launch_bounds__(256) void detect_dtype(const float* q, int* flag) {
  __shared__ int cnt;
  if (threadIdx.x == 0) cnt = 0;
  __syncthreads();
  int c = 0;
  for (int i = threadIdx.x; i < 1024; i += 256) {
    unsigned u = __float_as_uint(q[i]);
    unsigned e = (u >> 23) & 0xffu;
    if (e >= 104u && e <= 140u) c++;
  }
  atomicAdd(&cnt, c);
  __syncthreads();
  if (threadIdx.x == 0) *flag = (cnt > 512) ? 1 : 0;
}

// ---------------------------------------------------------------------------
// rbf bias: biasW[b,l,h,p] = rbf[b,l,p,:] @ Wr[:,h] + br[h].  Memory-bound.
// ---------------------------------------------------------------------------
__global__ __launch_bounds__(256) void rbf_bias_kernel(
    const void* __restrict__ rbf, const void* __restrict__ Wr,
    const void* __restrict__ br, float* __restrict__ biasW,
    const int* __restrict__ flag) {
  const bool f32 = (*flag != 0);
  __shared__ float wrS[NRBF * 8];
  __shared__ float brS[8];
  const int tid = threadIdx.x;
  for (int i = tid; i < NRBF * 8; i += 256) wrS[i] = ldf(Wr, i, f32);
  if (tid < 8) brS[tid] = ldf(br, tid, f32);
  __syncthreads();
  const size_t row = (size_t)blockIdx.x * 256 + tid;  // (b*L+l)*P + p
  float acc[8];
#pragma unroll
  for (int h = 0; h < 8; ++h) acc[h] = brS[h];
  if (f32) {
    const float2* rp = (const float2*)((const float*)rbf + row * NRBF);
#pragma unroll
    for (int j = 0; j < 25; ++j) {
      float2 r2 = rp[j];
      float4 wa = *(const float4*)&wrS[(2 * j) * 8];
      float4 wb = *(const float4*)&wrS[(2 * j) * 8 + 4];
      float4 wc = *(const float4*)&wrS[(2 * j + 1) * 8];
      float4 wd = *(const float4*)&wrS[(2 * j + 1) * 8 + 4];
      acc[0] = fmaf(r2.x, wa.x, acc[0]); acc[1] = fmaf(r2.x, wa.y, acc[1]);
      acc[2] = fmaf(r2.x, wa.z, acc[2]); acc[3] = fmaf(r2.x, wa.w, acc[3]);
      acc[4] = fmaf(r2.x, wb.x, acc[4]); acc[5] = fmaf(r2.x, wb.y, acc[5]);
      acc[6] = fmaf(r2.x, wb.z, acc[6]); acc[7] = fmaf(r2.x, wb.w, acc[7]);
      acc[0] = fmaf(r2.y, wc.x, acc[0]); acc[1] = fmaf(r2.y, wc.y, acc[1]);
      acc[2] = fmaf(r2.y, wc.z, acc[2]); acc[3] = fmaf(r2.y, wc.w, acc[3]);
      acc[4] = fmaf(r2.y, wd.x, acc[4]); acc[5] = fmaf(r2.y, wd.y, acc[5]);
      acc[6] = fmaf(r2.y, wd.z, acc[6]); acc[7] = fmaf(r2.y, wd.w, acc[7]);
    }
  } else {
    const __hip_bfloat16* rb = (const __hip_bfloat16*)rbf + row * NRBF;
#pragma unroll
    for (int j = 0; j < NRBF; ++j) {
      float r = __bfloat162float(rb[j]);
#pragma unroll
      for (int h = 0; h < 8; ++h) acc[h] = fmaf(r, wrS[j * 8 + h], acc[h]);
    }
  }
  const size_t bl = row >> 10;
  const int p = (int)(row & 1023);
#pragma unroll
  for (int h = 0; h < 8; ++h) biasW[(bl * 8 + h) * 1024 + p] = acc[h];
}

// ---------------------------------------------------------------------------
// Input projection: Y = X@W + b.  kt=0: Y[m][512] fp32.
// kt=1: transposed head-major output Kt[b][h][d][p] (m = b*1024+p, n = h*64+d)
// ---------------------------------------------------------------------------
__global__ __launch_bounds__(256) void proj_in(
    const void* __restrict__ X, const void* __restrict__ W,
    const void* __restrict__ bias, float* __restrict__ Y,
    const int* __restrict__ flag, const int kt) {
  __shared__ float As[16][64];  // [k][m]
  __shared__ float Bs[16][64];  // [k][n]
  const bool f32 = (*flag != 0);
  const int bm = blockIdx.x * 64, bn = blockIdx.y * 64;
  const int tid = threadIdx.x;
  const int tx = tid & 15, ty = tid >> 4;
  float acc[4][4] = {};
  for (int k0 = 0; k0 < 512; k0 += 16) {
    if (f32) {
      const float* Xf = (const float*)X;
      const float* Wf = (const float*)W;
      {
        int r = tid >> 2, kf = (tid & 3) * 4;
        float4 x4 = *(const float4*)(Xf + (size_t)(bm + r) * 512 + k0 + kf);
        As[kf + 0][r] = x4.x; As[kf + 1][r] = x4.y;
        As[kf + 2][r] = x4.z; As[kf + 3][r] = x4.w;
      }
      {
        int kk = tid >> 4, cf = (tid & 15) * 4;
        *(float4*)&Bs[kk][cf] =
            *(const float4*)(Wf + (size_t)(k0 + kk) * 512 + bn + cf);
      }
    } else {
      const __hip_bfloat16* Xb = (const __hip_bfloat16*)X;
      const __hip_bfloat16* Wb = (const __hip_bfloat16*)W;
      for (int f = tid; f < 64 * 16; f += 256) {
        int r = f >> 4, kk = f & 15;
        As[kk][r] = __bfloat162float(Xb[(size_t)(bm + r) * 512 + k0 + kk]);
      }
      for (int f = tid; f < 16 * 64; f += 256) {
        int kk = f >> 6, c = f & 63;
        Bs[kk][c] = __bfloat162float(Wb[(size_t)(k0 + kk) * 512 + bn + c]);
      }
    }
    __syncthreads();
#pragma unroll
    for (int k = 0; k < 16; ++k) {
      float4 a4 = *(const float4*)&As[k][ty * 4];
      float4 b4 = *(const float4*)&Bs[k][tx * 4];
      acc[0][0] = fmaf(a4.x, b4.x, acc[0][0]); acc[0][1] = fmaf(a4.x, b4.y, acc[0][1]);
      acc[0][2] = fmaf(a4.x, b4.z, acc[0][2]); acc[0][3] = fmaf(a4.x, b4.w, acc[0][3]);
      acc[1][0] = fmaf(a4.y, b4.x, acc[1][0]); acc[1][1] = fmaf(a4.y, b4.y, acc[1][1]);
      acc[1][2] = fmaf(a4.y, b4.z, acc[1][2]); acc[1][3] = fmaf(a4.y, b4.w, acc[1][3]);
      acc[2][0] = fmaf(a4.z, b4.x, acc[2][0]); acc[2][1] = fmaf(a4.z, b4.y, acc[2][1]);
      acc[2][2] = fmaf(a4.z, b4.z, acc[2][2]); acc[2][3] = fmaf(a4.z, b4.w, acc[2][3]);
      acc[3][0] = fmaf(a4.w, b4.x, acc[3][0]); acc[3][1] = fmaf(a4.w, b4.y, acc[3][1]);
      acc[3][2] = fmaf(a4.w, b4.z, acc[3][2]); acc[3][3] = fmaf(a4.w, b4.w, acc[3][3]);
    }
    __syncthreads();
  }
  if (kt) {
    // Kt[b][h][d][p]: h = bn>>6, d = tx*4+j, p = (bm&1023)+ty*4+i, b = bm>>10
    const int h = bn >> 6;
    const int bq = bm >> 10;
    const int p0 = (bm & 1023) + ty * 4;
#pragma unroll
    for (int j = 0; j < 4; ++j) {
      const float bb = ldf(bias, bn + tx * 4 + j, f32);
      float4 pv;
      pv.x = acc[0][j] + bb; pv.y = acc[1][j] + bb;
      pv.z = acc[2][j] + bb; pv.w = acc[3][j] + bb;
      *(float4*)(Y + (((size_t)bq * 8 + h) * 64 + tx * 4 + j) * 1024 + p0) = pv;
    }
  } else {
#pragma unroll
    for (int i = 0; i < 4; ++i) {
      int r = bm + ty * 4 + i;
      float4 o;
      o.x = acc[i][0] + ldf(bias, bn + tx * 4 + 0, f32);
      o.y = acc[i][1] + ldf(bias, bn + tx * 4 + 1, f32);
      o.z = acc[i][2] + ldf(bias, bn + tx * 4 + 2, f32);
      o.w = acc[i][3] + ldf(bias, bn + tx * 4 + 3, f32);
      *(float4*)(Y + (size_t)r * 512 + bn + tx * 4) = o;
    }
  }
}

// ---------------------------------------------------------------------------
// Output projection + residual: Xout = AO@Wo + bo + query   (fp32 ws)
// ---------------------------------------------------------------------------
__global__ __launch_bounds__(256) void proj_out(
    const float* __restrict__ X, const void* __restrict__ W,
    const void* __restrict__ bias, const void* __restrict__ resid,
    float* __restrict__ Y, const int* __restrict__ flag) {
  __shared__ float As[16][64];
  __shared__ float Bs[16][64];
  const bool f32 = (*flag != 0);
  const int bm = blockIdx.x * 64, bn = blockIdx.y * 64;
  const int tid = threadIdx.x;
  const int tx = tid & 15, ty = tid >> 4;
  float acc[4][4] = {};
  for (int k0 = 0; k0 < 512; k0 += 16) {
    {
      int r = tid >> 2, kf = (tid & 3) * 4;
      float4 x4 = *(const float4*)(X + (size_t)(bm + r) * 512 + k0 + kf);
      As[kf + 0][r] = x4.x; As[kf + 1][r] = x4.y;
      As[kf + 2][r] = x4.z; As[kf + 3][r] = x4.w;
    }
    if (f32) {
      int kk = tid >> 4, cf = (tid & 15) * 4;
      *(float4*)&Bs[kk][cf] =
          *(const float4*)((const float*)W + (size_t)(k0 + kk) * 512 + bn + cf);
    } else {
      const __hip_bfloat16* Wb = (const __hip_bfloat16*)W;
      for (int f = tid; f < 16 * 64; f += 256) {
        int kk = f >> 6, c = f & 63;
        Bs[kk][c] = __bfloat162float(Wb[(size_t)(k0 + kk) * 512 + bn + c]);
      }
    }
    __syncthreads();
#pragma unroll
    for (int k = 0; k < 16; ++k) {
      float4 a4 = *(const float4*)&As[k][ty * 4];
      float4 b4 = *(const float4*)&Bs[k][tx * 4];
      acc[0][0] = fmaf(a4.x, b4.x, acc[0][0]); acc[0][1] = fmaf(a4.x, b4.y, acc[0][1]);
      acc[0][2] = fmaf(a4.x, b4.z, acc[0][2]); acc[0][3] = fmaf(a4.x, b4.w, acc[0][3]);
      acc[1][0] = fmaf(a4.y, b4.x, acc[1][0]); acc[1][1] = fmaf(a4.y, b4.y, acc[1][1]);
      acc[1][2] = fmaf(a4.y, b4.z, acc[1][2]); acc[1][3] = fmaf(a4.y, b4.w, acc[1][3]);
      acc[2][0] = fmaf(a4.z, b4.x, acc[2][0]); acc[2][1] = fmaf(a4.z, b4.y, acc[2][1]);
      acc[2][2] = fmaf(a4.z, b4.z, acc[2][2]); acc[2][3] = fmaf(a4.z, b4.w, acc[2][3]);
      acc[3][0] = fmaf(a4.w, b4.x, acc[3][0]); acc[3][1] = fmaf(a4.w, b4.y, acc[3][1]);
      acc[3][2] = fmaf(a4.w, b4.z, acc[3][2]); acc[3][3] = fmaf(a4.w, b4.w, acc[3][3]);
    }
    __syncthreads();
  }
#pragma unroll
  for (int i = 0; i < 4; ++i) {
    int r = bm + ty * 4 + i;
    float4 o;
#pragma unroll
    for (int j = 0; j < 4; ++j) {
      int c = bn + tx * 4 + j;
      float v = acc[i][j] + ldf(bias, c, f32) +
                ldf(resid, (size_t)r * 512 + c, f32);
      ((float*)&o)[j] = v;
    }
    *(float4*)(Y + (size_t)r * 512 + bn + tx * 4) = o;
  }
}

// ---------------------------------------------------------------------------
// Attention v5: coalesced Kt reads; q read from LDS in-loop (no big register
// array — v4's qf[16] caused scratch spilling: FETCH 1.4GB/WRITE 2.2GB).
// ---------------------------------------------------------------------------
__global__ __launch_bounds__(256) void attn_v5(
    const float* __restrict__ Q,     // [B*L, 512]
    const float* __restrict__ Kt,    // [B][8][64][1024]
    const float* __restrict__ V,     // [B*P, 512]
    const float* __restrict__ biasW, // [B*L][8][1024]
    const int* __restrict__ mask,    // [B,P]
    float* __restrict__ AO,          // [B*L, 512]
    void* __restrict__ d_out, const int* __restrict__ flag) {
  const int xcd = blockIdx.x & 7;
  const int idx = blockIdx.x >> 3;
  const int b = xcd >> 1;
  const int l = ((xcd & 1) << 7) | idx;
  const int bl = b * LL + l;
  const int t = threadIdx.x;
  const bool f32 = (*flag != 0);

  __shared__ float qS[512];
  __shared__ float scoresS[HH * PP];    // 32 KB
  __shared__ float partsS[2 * 128 * 4]; // 4 KB

  for (int i = t; i < 512; i += 256) qS[i] = Q[(size_t)bl * 512 + i];
  __syncthreads();

  // ---- score phase: thread owns p in {4t..4t+3}, loops all 8 heads ----
  {
    const int4 mk4 = *(const int4*)(mask + b * PP + 4 * t);
#pragma unroll 1
    for (int h = 0; h < 8; ++h) {
      const float4* ktp =
          (const float4*)(Kt + (((size_t)b * 8 + h) * 64) * 1024) + t;
      float4 acc = {0.f, 0.f, 0.f, 0.f};
#pragma unroll 2
      for (int dq = 0; dq < 16; ++dq) {
        float4 q4 = *(const float4*)&qS[h * 64 + dq * 4];  // uniform bcast
        float4 k0 = ktp[(size_t)(dq * 4 + 0) * 256];
        float4 k1 = ktp[(size_t)(dq * 4 + 1) * 256];
        float4 k2 = ktp[(size_t)(dq * 4 + 2) * 256];
        float4 k3 = ktp[(size_t)(dq * 4 + 3) * 256];
        acc.x = fmaf(q4.x, k0.x, acc.x); acc.y = fmaf(q4.x, k0.y, acc.y);
        acc.z = fmaf(q4.x, k0.z, acc.z); acc.w = fmaf(q4.x, k0.w, acc.w);
        acc.x = fmaf(q4.y, k1.x, acc.x); acc.y = fmaf(q4.y, k1.y, acc.y);
        acc.z = fmaf(q4.y, k1.z, acc.z); acc.w = fmaf(q4.y, k1.w, acc.w);
        acc.x = fmaf(q4.z, k2.x, acc.x); acc.y = fmaf(q4.z, k2.y, acc.y);
        acc.z = fmaf(q4.z, k2.z, acc.z); acc.w = fmaf(q4.z, k2.w, acc.w);
        acc.x = fmaf(q4.w, k3.x, acc.x); acc.y = fmaf(q4.w, k3.y, acc.y);
        acc.z = fmaf(q4.w, k3.z, acc.z); acc.w = fmaf(q4.w, k3.w, acc.w);
      }
      float4 b4 = *(const float4*)&biasW[((size_t)bl * 8 + h) * 1024 + 4 * t];
      float4 s;
      s.x = (mk4.x == 0) ? -1e9f : fmaf(acc.x, 0.125f, b4.x);
      s.y = (mk4.y == 0) ? -1e9f : fmaf(acc.y, 0.125f, b4.y);
      s.z = (mk4.z == 0) ? -1e9f : fmaf(acc.z, 0.125f, b4.z);
      s.w = (mk4.w == 0) ? -1e9f : fmaf(acc.w, 0.125f, b4.w);
      *(float4*)&scoresS[h * 1024 + 4 * t] = s;
    }
  }
  __syncthreads();

  // ---- softmax per head; wave w handles heads 2w,2w+1 ----
  const int wave = t >> 6, lane = t & 63;
  for (int hh = wave * 2; hh < wave * 2 + 2; ++hh) {
    float* sc = &scoresS[hh * 1024];
    float m = -3.0e38f;
    for (int i = lane; i < PP; i += 64) m = fmaxf(m, sc[i]);
#pragma unroll
    for (int off = 32; off; off >>= 1) m = fmaxf(m, __shfl_xor(m, off, 64));
    float sum = 0.f;
    for (int i = lane; i < PP; i += 64) {
      float e = __expf(sc[i] - m);
      sc[i] = e;
      sum += e;
    }
#pragma unroll
    for (int off = 32; off; off >>= 1) sum += __shfl_xor(sum, off, 64);
    const float inv = 1.0f / sum;
    for (int i = lane; i < PP; i += 64) sc[i] *= inv;
  }
  __syncthreads();

  // ---- attn_mean: thread owns 4 consecutive p ----
  {
    float4 s = {0.f, 0.f, 0.f, 0.f};
#pragma unroll
    for (int hh = 0; hh < HH; ++hh) {
      float4 v = *(const float4*)&scoresS[hh * 1024 + t * 4];
      s.x += v.x; s.y += v.y; s.z += v.z; s.w += v.w;
    }
    s.x *= 0.125f; s.y *= 0.125f; s.z *= 0.125f; s.w *= 0.125f;
    const size_t base = (size_t)BB * LL * DD + (size_t)bl * PP + t * 4;
    if (f32) {
      *(float4*)((float*)d_out + base) = s;
    } else {
      __hip_bfloat16* o1 = (__hip_bfloat16*)d_out;
      o1[base + 0] = __float2bfloat16(s.x);
      o1[base + 1] = __float2bfloat16(s.y);
      o1[base + 2] = __float2bfloat16(s.z);
      o1[base + 3] = __float2bfloat16(s.w);
    }
  }

  // ---- PV: thread owns c-quad (cq = t&127) and p-half (ph = t>>7) ----
  {
    const int cq = t & 127;
    const int ph = t >> 7;
    const int h = cq >> 4;
    const float* sc = &scoresS[h * 1024];
    const float4* Vb =
        (const float4*)(V + (size_t)b * PP * 512) + cq;  // stride 128 f4 per p
    float4 acc = {0.f, 0.f, 0.f, 0.f};
    const int p0 = ph * 512;
#pragma unroll 2
    for (int p4 = p0; p4 < p0 + 512; p4 += 4) {
      float4 pr = *(const float4*)&sc[p4];
      float4 v0 = Vb[(size_t)(p4 + 0) * 128];
      float4 v1 = Vb[(size_t)(p4 + 1) * 128];
      float4 v2 = Vb[(size_t)(p4 + 2) * 128];
      float4 v3 = Vb[(size_t)(p4 + 3) * 128];
      acc.x = fmaf(pr.x, v0.x, acc.x); acc.y = fmaf(pr.x, v0.y, acc.y);
      acc.z = fmaf(pr.x, v0.z, acc.z); acc.w = fmaf(pr.x, v0.w, acc.w);
      acc.x = fmaf(pr.y, v1.x, acc.x); acc.y = fmaf(pr.y, v1.y, acc.y);
      acc.z = fmaf(pr.y, v1.z, acc.z); acc.w = fmaf(pr.y, v1.w, acc.w);
      acc.x = fmaf(pr.z, v2.x, acc.x); acc.y = fmaf(pr.z, v2.y, acc.y);
      acc.z = fmaf(pr.z, v2.z, acc.z); acc.w = fmaf(pr.z, v2.w, acc.w);
      acc.x = fmaf(pr.w, v3.x, acc.x); acc.y = fmaf(pr.w, v3.y, acc.y);
      acc.z = fmaf(pr.w, v3.z, acc.z); acc.w = fmaf(pr.w, v3.w, acc.w);
    }
    *(float4*)&partsS[(ph * 128 + cq) * 4] = acc;
  }
  __syncthreads();
  if (t < 128) {
    float4 a = *(const float4*)&partsS[t * 4];
    float4 bb = *(const float4*)&partsS[(128 + t) * 4];
    a.x += bb.x; a.y += bb.y; a.z += bb.z; a.w += bb.w;
    *(float4*)(AO + (size_t)bl * 512 + t * 4) = a;
  }
}

// ---------------------------------------------------------------------------
// LayerNorm rows of Xw -> out0
// ---------------------------------------------------------------------------
__global__ __launch_bounds__(256) void ln_kernel(
    const float* __restrict__ Xw, const void* __restrict__ gamma,
    const void* __restrict__ beta, void* __restrict__ d_out,
    const int* __restrict__ flag) {
  const int bl = blockIdx.x;
  const int tid = threadIdx.x;
  const bool f32 = (*flag != 0);
  __shared__ float red[16];
  float v0 = Xw[(size_t)bl * 512 + tid];
  float v1 = Xw[(size_t)bl * 512 + tid + 256];
  float s = v0 + v1, s2 = v0 * v0 + v1 * v1;
#pragma unroll
  for (int off = 32; off; off >>= 1) {
    s += __shfl_xor(s, off, 64);
    s2 += __shfl_xor(s2, off, 64);
  }
  const int wave = tid >> 6, lane = tid & 63;
  if (lane == 0) { red[wave] = s; red[8 + wave] = s2; }
  __syncthreads();
  if (tid == 0) {
    float ts = 0.f, ts2 = 0.f;
    for (int w = 0; w < 4; ++w) { ts += red[w]; ts2 += red[8 + w]; }
    red[0] = ts; red[1] = ts2;
  }
  __syncthreads();
  const float mu = red[0] * (1.0f / 512.0f);
  const float var = red[1] * (1.0f / 512.0f) - mu * mu;
  const float rstd = rsqrtf(var + 1e-5f);
  float o0 = (v0 - mu) * rstd * ldf(gamma, tid, f32) + ldf(beta, tid, f32);
  float o1 = (v1 - mu) * rstd * ldf(gamma, tid + 256, f32) +
             ldf(beta, tid + 256, f32);
  if (f32) {
    float* o = (float*)d_out;
    o[(size_t)bl * 512 + tid] = o0;
    o[(size_t)bl * 512 + tid + 256] = o1;
  } else {
    __hip_bfloat16* o = (__hip_bfloat16*)d_out;
    o[(size_t)bl * 512 + tid] = __float2bfloat16(o0);
    o[(size_t)bl * 512 + tid + 256] = __float2bfloat16(o1);
  }
}

// ---------------------------------------------------------------------------
extern "C" void kernel_launch(void* const* d_in, const int* in_sizes, int n_in,
                              void* d_out, int out_size, void* d_ws,
                              size_t ws_size, hipStream_t stream) {
  const void* query = d_in[0];
  const void* key = d_in[1];
  const void* value = d_in[2];
  const void* rbf = d_in[3];
  const int* key_mask = (const int*)d_in[4];
  const void* Wq = d_in[5];
  const void* bq = d_in[6];
  const void* Wk = d_in[7];
  const void* bk = d_in[8];
  const void* Wv = d_in[9];
  const void* bv = d_in[10];
  const void* Wr = d_in[11];
  const void* br = d_in[12];
  const void* Wo = d_in[13];
  const void* bo = d_in[14];
  const void* gamma = d_in[15];
  const void* beta = d_in[16];

  // ws: [flag 16B] Q | Kt | V | AO | X | biasW
  int* flag = (int*)d_ws;
  float* base = (float*)d_ws + 4;
  float* Qw = base;
  float* Ktw = Qw + (size_t)BB * LL * DD;   // +524288
  float* Vw = Ktw + (size_t)BB * PP * DD;   // +2097152
  float* AO = Vw + (size_t)BB * PP * DD;    // +2097152
  float* Xw = AO + (size_t)BB * LL * DD;    // +524288
  float* biasW = Xw + (size_t)BB * LL * DD; // +524288

  detect_dtype<<<1, 256, 0, stream>>>((const float*)query, flag);
  proj_in<<<dim3(16, 8), 256, 0, stream>>>(query, Wq, bq, Qw, flag, 0);
  proj_in<<<dim3(64, 8), 256, 0, stream>>>(key, Wk, bk, Ktw, flag, 1);
  proj_in<<<dim3(64, 8), 256, 0, stream>>>(value, Wv, bv, Vw, flag, 0);
  rbf_bias_kernel<<<dim3(BB * LL * PP / 256), 256, 0, stream>>>(rbf, Wr, br,
                                                                biasW, flag);
  attn_v5<<<dim3(BB * LL), 256, 0, stream>>>(Qw, Ktw, Vw, biasW, key_mask, AO,
                                             d_out, flag);
  proj_out<<<dim3(16, 8), 256, 0, stream>>>(AO, Wo, bo, query, Xw, flag);
  ln_kernel<<<dim3(BB * LL), 256, 0, stream>>>(Xw, gamma, beta, d_out, flag);
}